// Round 10
// baseline (102.414 us; speedup 1.0000x reference)
//
#include <hip/hip_runtime.h>

// Reference constants
#define NUM_EMB    8192
#define EMB_DIM    512
#define BATCH_N    16384
#define BD         (BATCH_N * EMB_DIM)   // 8388608 elems in quantized (and diff)
#define TOTAL_OUT  (2 * BD + 1)          // 16777217 fp32 elems in d_out
#define NCHUNK     (TOTAL_OUT / 4)       // 4194304 full float4 chunks (+1 tail)
#define QCHUNK_END (BD / 4)              // 2097152: boundary chunk index
#define NBLOCKS    2048
#define NTHREADS   256
#define NTOTAL     (NBLOCKS * NTHREADS)  // 524288 threads = 8192 waves

// clang vector type — accepted by __builtin_nontemporal_store (HIP float4 is not)
typedef float vf4 __attribute__((ext_vector_type(4)));

__device__ float g_partial[NBLOCKS];     // K1->K2 handoff (validated R2/R4/R5)

__device__ __forceinline__ void nt_store4(vf4* p, float a, float b, float c, float d) {
    vf4 v; v.x = a; v.y = b; v.z = c; v.w = d;
    __builtin_nontemporal_store(v, p);
}

// ---- K1: per-block partial sums of W^2 (16 MB fp32 stream, ~3 us).
// Normal (allocating) loads on purpose: warms LLC with W for K2. ----
__global__ __launch_bounds__(NTHREADS) void vq_sum(const float* __restrict__ W) {
    int tid = blockIdx.x * NTHREADS + threadIdx.x;
    const float4* W4 = (const float4*)W;
    float4 a = W4[tid];
    float4 b = W4[tid + NTOTAL];
    float s = a.x*a.x + a.y*a.y + a.z*a.z + a.w*a.w
            + b.x*b.x + b.y*b.y + b.z*b.z + b.w*b.w;
#pragma unroll
    for (int off = 32; off > 0; off >>= 1) s += __shfl_down(s, off, 64);
    __shared__ float ls[NTHREADS / 64];
    if ((threadIdx.x & 63) == 0) ls[threadIdx.x >> 6] = s;
    __syncthreads();
    if (threadIdx.x == 0) g_partial[blockIdx.x] = ls[0] + ls[1] + ls[2] + ls[3];
}

// ---- K2: R5's row-streaming writer, ALL output stores nontemporal (nt bit:
// no LLC allocation). Probe: does dodging the poison-dirtied LLC recover the
// ~25 us gap between measured (~40 us) and roofline (~15 us)? ----
__global__ __launch_bounds__(NTHREADS) void vq_write(const int* __restrict__ x,
        const float* __restrict__ W, float* __restrict__ out) {
    const int tid  = blockIdx.x * NTHREADS + threadIdx.x;
    const int lane = threadIdx.x & 63;
    const int wave = (tid >> 6);               // 0..8191
    vf4* out4 = (vf4*)out;

    const int b0 = 2 * wave;
    const int b1 = 2 * wave + 1;

    // row-index loads first (broadcast; tiny)
    int k0 = x[b0];
    int k1 = x[b1];
    int kp = (b0 > 0) ? x[b0 - 1] : 0;

    // Diff region: 2097151 zero chunks, nt fire-and-forget stores.
#pragma unroll
    for (int k = 0; k < 4; ++k) {
        int c = QCHUNK_END + 1 + tid + k * NTOTAL;
        if (c < NCHUNK) nt_store4(&out4[c], 0.f, 0.f, 0.f, 0.f);
    }
    if (blockIdx.x == 1 && threadIdx.x == 0) {
        __builtin_nontemporal_store(0.0f, &out[TOTAL_OUT - 1]); // odd tail elem
        float w = W[x[BATCH_N - 1] * EMB_DIM + 511];            // boundary chunk
        nt_store4(&out4[QCHUNK_END], w, 0.f, 0.f, 0.f);
    }

    // Row data (normal loads; W is LLC-warm from K1).
    const float4* R0 = (const float4*)(W + k0 * EMB_DIM);
    const float4* R1 = (const float4*)(W + k1 * EMB_DIM);
    float4 a0 = R0[2 * lane], a1 = R0[2 * lane + 1];
    float4 c0 = R1[2 * lane], c1 = R1[2 * lane + 1];
    float p0 = W[kp * EMB_DIM + 511];          // prev-row elem 511
    float p1 = W[k0 * EMB_DIM + 511];          // row b0 elem 511

    // Row b0: lane l covers row elems 8l..8l+7 -> chunks 128*b0 + 2l, +2l+1.
    {
        float pw = __shfl_up(a1.w, 1, 64);
        float first = (lane == 0) ? p0 : pw;
        int cb = 128 * b0;
        if (b0 != 0 || lane != 0)              // chunk 0 is the loss chunk
            nt_store4(&out4[cb + 2 * lane], first, a0.x, a0.y, a0.z);
        nt_store4(&out4[cb + 2 * lane + 1], a0.w, a1.x, a1.y, a1.z);
    }
    // Row b1
    {
        float prev1 = __shfl(a1.w, 63, 64);    // row b0 elem 511
        float pw = __shfl_up(c1.w, 1, 64);
        float first = (lane == 0) ? prev1 : pw;
        int cb = 128 * b1;
        nt_store4(&out4[cb + 2 * lane], first, c0.x, c0.y, c0.z);
        nt_store4(&out4[cb + 2 * lane + 1], c0.w, c1.x, c1.y, c1.z);
    }

    // Block 0: reduce partials -> loss, sole writer of chunk 0.
    if (blockIdx.x == 0) {
        __shared__ float red[NTHREADS];
        float s = 0.0f;
        for (int i = threadIdx.x; i < NBLOCKS; i += NTHREADS) s += g_partial[i];
        red[threadIdx.x] = s;
        __syncthreads();
        for (int st = NTHREADS / 2; st > 0; st >>= 1) {
            if (threadIdx.x < st) red[threadIdx.x] += red[threadIdx.x + st];
            __syncthreads();
        }
        if (threadIdx.x == 0) {
            float loss = 0.25f * red[0];       // diff loss term is exactly 0
            int k = x[0];
            float4 v = *(const float4*)(W + k * EMB_DIM);
            nt_store4(&out4[0], loss, v.x, v.y, v.z);
        }
    }
}

extern "C" void kernel_launch(void* const* d_in, const int* in_sizes, int n_in,
                              void* d_out, int out_size, void* d_ws, size_t ws_size,
                              hipStream_t stream) {
    const int*   x = (const int*)d_in[0];    // int32 indices, 16384
    const float* W = (const float*)d_in[1];  // fp32 codebook, 8192x512
    float* out     = (float*)d_out;          // fp32: [loss | quantized | diff]

    vq_sum<<<NBLOCKS, NTHREADS, 0, stream>>>(W);
    vq_write<<<NBLOCKS, NTHREADS, 0, stream>>>(x, W, out);
}